// Round 6
// baseline (243.798 us; speedup 1.0000x reference)
//
#include <hip/hip_runtime.h>

// LIF scan over T=16: mem_t = beta*mem + x_t - spk_{t-1}; spk_t = (mem_t - 1) > 0.
// Neurons independent -> 1 thread owns 4 neurons across all T.
//
// R9: store-ack decoupling. Evidence: fillBufferAligned hits 6.66 TB/s
// write-only in the SAME profile where we plateau at 2.45 TB/s with VALUBusy
// 4.5%; implied per-wave stall (~10 us) is far beyond load latency -> waves
// are waiting on STORE ACKS. vmcnt is one in-order FIFO counting loads AND
// stores; the rolled schedule interleaves store(t) between loads, so every
// s_waitcnt guarding a load consumer transitively waits for earlier stores to
// be acked by the (backpressured) write path. Fix: fence ONLY the spk results
// (asm operand-tie) so all 16 stores sit strictly after the last load consume
// -- loads keep the compiler's optimal rolling schedule (R5's load-fence
// vmcnt(0) drain mistake is NOT repeated). launch_bounds(256,4) = 128-VGPR
// budget so 16 live spk f4s (64 VGPR) don't spill; 4 waves/EU as measured.

constexpr int   T      = 16;
constexpr float BETA   = 0.9f;
constexpr float THRESH = 1.0f;

typedef float f4 __attribute__((ext_vector_type(4)));

__global__ __launch_bounds__(256, 4) void lif_kernel(const float* __restrict__ x,
                                                     float* __restrict__ out,
                                                     int n_per_t) {
    // No FMA contraction: must match numpy's two-rounding fp32 exactly, else
    // ~1-ulp drift flips spikes at the threshold (absmax = 1.0 cascades).
#pragma clang fp contract(off)
    const int idx = (blockIdx.x * blockDim.x + threadIdx.x) * 4;
    if (idx >= n_per_t) return;

    f4 v[T];  // x_t on the way in, spk_t on the way out

    // Load + recurrence: UNFENCED — compiler keeps its rolling MLP~4 pipeline
    // (every variant that constrained this phase measured 25% worse, R4-R6).
#pragma unroll
    for (int t = 0; t < T; ++t) {
        v[t] = *reinterpret_cast<const f4*>(x + (size_t)t * (size_t)n_per_t + (size_t)idx);
    }

    f4 mem = (f4)(0.f);
    f4 spk = (f4)(0.f);
#pragma unroll
    for (int t = 0; t < T; ++t) {
#pragma unroll
        for (int j = 0; j < 4; ++j) {
            mem[j] = BETA * mem[j] + v[t][j] - spk[j] * THRESH;
            spk[j] = (mem[j] - THRESH) > 0.f ? 1.f : 0.f;
        }
        v[t] = spk;
    }

    // Fence ONLY the results: stores' data defs pass through this asm, so no
    // store can be hoisted up into the load/compute loop -> the vmcnt FIFO
    // during load consumption contains loads only; store acks leave the
    // critical path. Loads/compute above are completely unconstrained.
    asm volatile("" : "+v"(v[0]), "+v"(v[1]), "+v"(v[2]), "+v"(v[3]),
                      "+v"(v[4]), "+v"(v[5]), "+v"(v[6]), "+v"(v[7]),
                      "+v"(v[8]), "+v"(v[9]), "+v"(v[10]), "+v"(v[11]),
                      "+v"(v[12]), "+v"(v[13]), "+v"(v[14]), "+v"(v[15]));

    // Store burst: 16 plain stores, no waits needed (kernel end drains).
#pragma unroll
    for (int t = 0; t < T; ++t) {
        *reinterpret_cast<f4*>(out + (size_t)t * (size_t)n_per_t + (size_t)idx) = v[t];
    }
}

extern "C" void kernel_launch(void* const* d_in, const int* in_sizes, int n_in,
                              void* d_out, int out_size, void* d_ws, size_t ws_size,
                              hipStream_t stream) {
    const float* x   = (const float*)d_in[0];
    float*       out = (float*)d_out;

    const int total   = in_sizes[0];      // 33,554,432
    const int n_per_t = total / T;        // 2,097,152 (divisible by 4)
    const int threads = n_per_t / 4;      // 524,288

    dim3 block(256);
    dim3 grid((threads + block.x - 1) / block.x);  // 2048 blocks
    lif_kernel<<<grid, block, 0, stream>>>(x, out, n_per_t);
}

// Round 9
// 226.895 us; speedup vs baseline: 1.0745x; 1.0745x over previous
//
#include <hip/hip_runtime.h>

// LIF scan over T=16: mem_t = beta*mem + x_t - spk_{t-1}; spk_t = (mem_t - 1) > 0.
// Neurons independent -> 1 thread owns 16 neurons (4 dense f4 chunks) across all T.
//
// R12 = R10/R11 re-run (both prior attempts died on "MI355X container failed
// twice" -- acquisition-level, no compile/correctness signal; session infra has
// been flaky throughout). Kernel audited for hang pathologies: none (all
// threads reach all barriers, no runtime indexing, tiny code). Single hygiene
// change vs R11: outer pass loop is a REAL loop now (not unrolled) -- barriers
// already prevent cross-pass scheduling, so unrolling bought nothing; smaller
// kernel removes any residual compile-size risk.
//
// Experiment (unchanged): R/W phase separation via barriers. Plateau 81-84 us
// (2.47 TB/s fabric) is invariant to occupancy (50<->16%), run length
// (4->16 KB), store policy (NT/plain); per-wave asm fences LOSE 10-25%.
// Same-profile refs: fillBuffer 6.66 TB/s write-only, dense copy 6.29 TB/s.
// Remaining structural difference vs copy: fine-grained R/W interleave across
// ~32 strided 8MB regions per DRAM channel (rolled schedule mixes store(t)
// between load(t+k)) -> bus-turnaround + row-thrash efficiency loss.
// Fix attempt: per pass, [8 loads + compute] / barrier / [8-store burst] /
// barrier. Loads can't hoist above a barrier, stores can't sink below one --
// plain C semantics, compiler free to roll WITHIN each region. 2 blocks/CU
// phase-offset keep both directions busy chip-wide while each wave's request
// train is unidirectional.
// Mechanism check: VGPR must jump to ~70-104. Null at 81-86 us with VGPR high
// -> pattern envelope established -> roofline. ~92 us -> revert to R8.

constexpr int   T      = 16;
constexpr float BETA   = 0.9f;
constexpr float THRESH = 1.0f;

typedef float f4 __attribute__((ext_vector_type(4)));

__global__ __launch_bounds__(256, 4) void lif_kernel(const float* __restrict__ x,
                                                     float* __restrict__ out,
                                                     int n_per_t) {
    // No FMA contraction: must match numpy's two-rounding fp32 exactly, else
    // ~1-ulp drift flips spikes at the threshold (absmax = 1.0 cascades).
#pragma clang fp contract(off)
    // R8 geometry (measured best): block owns 4096 consecutive floats per
    // plane as 4 chunks of 1024; thread owns 4 f4 slots at c*1024 + tid*4.
    // Clamp (not early-return) so every thread reaches the barriers; with
    // n_per_t = 2,097,152 and 512 blocks the clamp never actually engages.
    int base = blockIdx.x * 4096 + threadIdx.x * 4;
    if (base + 3072 + 4 > n_per_t) base = 0;  // degenerate-safe duplicate work

    // Persistent recurrence state, registers only.
    f4 m[4] = {(f4)(0.f), (f4)(0.f), (f4)(0.f), (f4)(0.f)};
    f4 s[4] = {(f4)(0.f), (f4)(0.f), (f4)(0.f), (f4)(0.f)};

    for (int pass = 0; pass < 8; ++pass) {
        const int t0 = pass * 2;

        // READ region: 8 coalesced f4 loads (2 planes x 4 chunks), one burst.
        f4 r[2][4];
#pragma unroll
        for (int p = 0; p < 2; ++p) {
            const size_t off = (size_t)(t0 + p) * (size_t)n_per_t + (size_t)base;
#pragma unroll
            for (int c = 0; c < 4; ++c)
                r[p][c] = *reinterpret_cast<const f4*>(x + off + c * 1024);
        }

        // Compute: 2 recurrence steps; results overwrite r.
#pragma unroll
        for (int p = 0; p < 2; ++p) {
#pragma unroll
            for (int c = 0; c < 4; ++c) {
#pragma unroll
                for (int j = 0; j < 4; ++j) {
                    m[c][j] = BETA * m[c][j] + r[p][c][j] - s[c][j] * THRESH;
                    s[c][j] = (m[c][j] - THRESH) > 0.f ? 1.f : 0.f;
                }
                r[p][c] = s[c];
            }
        }

        // Region boundary: stores may not hoist above, loads may not sink below.
        __syncthreads();

        // WRITE region: 8-store unidirectional burst (plain cacheable stores).
#pragma unroll
        for (int p = 0; p < 2; ++p) {
            const size_t off = (size_t)(t0 + p) * (size_t)n_per_t + (size_t)base;
#pragma unroll
            for (int c = 0; c < 4; ++c)
                *reinterpret_cast<f4*>(out + off + c * 1024) = r[p][c];
        }

        // Region boundary: next pass's loads stay after this store burst.
        __syncthreads();
    }
}

extern "C" void kernel_launch(void* const* d_in, const int* in_sizes, int n_in,
                              void* d_out, int out_size, void* d_ws, size_t ws_size,
                              hipStream_t stream) {
    const float* x   = (const float*)d_in[0];
    float*       out = (float*)d_out;

    const int total   = in_sizes[0];      // 33,554,432
    const int n_per_t = total / T;        // 2,097,152 (divisible by 4096)
    const int blocks  = n_per_t / 4096;   // 512 blocks, 256 threads, 16 floats/thread

    lif_kernel<<<dim3(blocks), dim3(256), 0, stream>>>(x, out, n_per_t);
}